// Round 8
// baseline (2090.904 us; speedup 1.0000x reference)
//
#include <hip/hip_runtime.h>
#include <math.h>

#define SEQ 512
#define HID 512
#define NGROUP 8              // batch groups of 16; group g = bid & 7
#define GB 16                 // batches per group
#define BPG 32                // blocks per group (each owns 16 n-cols)
#define SLOTW 65536           // tagged words per slot (8 groups * 8192)
#define GSLOTW 8192           // words per group per slot ([b16][k512], 4 B each)
#define LROW 520              // LDS row stride in ushorts (512 + 8 pad) - proven layout
// ws layout: [0, 512 KB) two TAGGED H slots: word = bf16(H) | step_tag << 16.
// The tag IS the synchronization: no flags, no producer drain, no flag RT.

typedef __attribute__((ext_vector_type(8))) short short8;   // 8 bf16 = 4 VGPRs (MFMA A/B)
typedef __attribute__((ext_vector_type(4))) float floatx4;  // MFMA C/D

__device__ __forceinline__ unsigned short f2bf(float f) {   // RNE fp32->bf16
    unsigned u = __builtin_bit_cast(unsigned, f);
    return (unsigned short)((u + 0x7FFFu + ((u >> 16) & 1u)) >> 16);
}
__device__ __forceinline__ float bf2f(unsigned short h) {
    unsigned u = ((unsigned)h) << 16;
    return __builtin_bit_cast(float, u);
}
__device__ __forceinline__ float fast_sigmoid(float x) {
    return 1.0f / (1.0f + __expf(-x));
}
__device__ __forceinline__ float fast_tanh(float x) {       // stable for |x| large
    float e = __expf(-2.0f * fabsf(x));
    float t = (1.0f - e) / (1.0f + e);
    return x < 0.0f ? -t : t;
}
__device__ __forceinline__ unsigned pk(unsigned lo, unsigned hi) {  // 2 tagged -> 1 bf16x2
    return (lo & 0xFFFFu) | (hi << 16);
}

__global__ void lstm_init(const float* __restrict__ H0, unsigned* __restrict__ hw) {
    int idx = blockIdx.x * blockDim.x + threadIdx.x;
    if (idx < SLOTW) {
        int k = idx & 511, b = (idx >> 9) & 15, g = idx >> 13;
        hw[idx] = (unsigned)f2bf(H0[(g * GB + b) * HID + k]);   // tag 0 | H0
    } else if (idx < 2 * SLOTW) {
        hw[idx] = 0xFFFF0000u;                                  // invalid tag (!= any t)
    }
}

__global__ __launch_bounds__(256, 1)
void lstm_main(const float* __restrict__ x,
               const float* __restrict__ C0,
               const float* __restrict__ Wi, const float* __restrict__ bi,
               const float* __restrict__ Wf, const float* __restrict__ bf_,
               const float* __restrict__ Wc, const float* __restrict__ bc,
               const float* __restrict__ Wo, const float* __restrict__ bo,
               float* __restrict__ out, unsigned* __restrict__ hw) {
    const int bid  = blockIdx.x;
    const int g    = bid & 7;
    const int cb   = bid >> 3;
    const int tid  = threadIdx.x;
    const int w    = tid >> 6;          // wave 0..3 (owns cols cb*16+w*4 .. +3)
    const int lane = tid & 63;
    const int q    = lane >> 4;         // quad
    const int c    = lane & 15;         // low lane bits

    // MFMA index roles (m89/m91/m120-verified layouts):
    //   A-frag: lane holds A[m = lane&15][k = quad*8+j]   (m = col_local*4 + gate)
    //   B-frag: lane holds B[k = quad*8+j][n = lane&15]   (n = batch)
    //   D:      lane holds D[m = quad*4+r][n = lane&15]   (r = gate, col_local = quad)
    const int gate = c & 3;                       // for A-frag build
    const int colA = cb * 16 + w * 4 + (c >> 2);  // A-frag column
    const int colD = cb * 16 + w * 4 + q;         // this lane's output column
    const int bD   = g * GB + c;                  // this lane's batch

    // ---- A-fragments: hi+lo bf16 split of W, step-invariant, in registers ----
    const float* Wg = (gate == 0) ? Wi : (gate == 1) ? Wf : (gate == 2) ? Wc : Wo;
    short8 aHi[16], aLo[16];
    #pragma unroll
    for (int kt = 0; kt < 16; ++kt) {
        #pragma unroll
        for (int j = 0; j < 8; ++j) {
            int k = kt * 32 + q * 8 + j;
            float wv = Wg[(k + 1) * HID + colA];   // rows 1..512 are H weights
            unsigned short hi = f2bf(wv);
            unsigned short lo = f2bf(wv - bf2f(hi));
            aHi[kt][j] = (short)hi;
            aLo[kt][j] = (short)lo;
        }
    }

    // epilogue constants (row 0 = x weight, bias) + C state, all for (colD, bD)
    const float biasI = bi[colD], biasF = bf_[colD], biasC = bc[colD], biasO = bo[colD];
    const float w0I = Wi[colD], w0F = Wf[colD], w0C = Wc[colD], w0O = Wo[colD];
    float Cst = C0[bD * HID + colD];
    const float* xrow = x + bD * SEQ;

    // Double-buffered H tile (33 KB). Dependency argument: a wave can only stage
    // step t+2 (same buffer as t) after every wave of its block produced H_{t+2},
    // which requires their GEMM t+1, which follows their reads of buffer t&1.
    __shared__ __align__(16) unsigned short hlds[2][16 * LROW];

    const int b_row = tid >> 4, ch = tid & 15;
    const unsigned* gsrc_base = hw + g * GSLOTW + b_row * 512 + ch * 32;
    unsigned* pdst_base = hw + g * GSLOTW + c * 512 + colD;   // producer word

    for (int t = 0; t < SEQ; ++t) {
        // ---- poll+stage fused: re-load OWN 128 B until all 32 tags == t.
        //      Distinct addresses per thread: no hot-line contention (r4/r6 lesson).
        {
            const unsigned* gsrc = gsrc_base + (t & 1) * SLOTW;
            int4 a0, a1, a2, a3, a4, a5, a6, a7;
            const unsigned tt = (unsigned)t << 16;
            for (;;) {
                asm volatile(
                    "global_load_dwordx4 %0, %8, off sc0 sc1\n\t"
                    "global_load_dwordx4 %1, %8, off offset:16 sc0 sc1\n\t"
                    "global_load_dwordx4 %2, %8, off offset:32 sc0 sc1\n\t"
                    "global_load_dwordx4 %3, %8, off offset:48 sc0 sc1\n\t"
                    "global_load_dwordx4 %4, %8, off offset:64 sc0 sc1\n\t"
                    "global_load_dwordx4 %5, %8, off offset:80 sc0 sc1\n\t"
                    "global_load_dwordx4 %6, %8, off offset:96 sc0 sc1\n\t"
                    "global_load_dwordx4 %7, %8, off offset:112 sc0 sc1\n\t"
                    "s_waitcnt vmcnt(0)"
                    : "=&v"(a0), "=&v"(a1), "=&v"(a2), "=&v"(a3),
                      "=&v"(a4), "=&v"(a5), "=&v"(a6), "=&v"(a7)
                    : "v"(gsrc) : "memory");
                unsigned xr =
                    ((unsigned)a0.x ^ tt) | ((unsigned)a0.y ^ tt) |
                    ((unsigned)a0.z ^ tt) | ((unsigned)a0.w ^ tt) |
                    ((unsigned)a1.x ^ tt) | ((unsigned)a1.y ^ tt) |
                    ((unsigned)a1.z ^ tt) | ((unsigned)a1.w ^ tt) |
                    ((unsigned)a2.x ^ tt) | ((unsigned)a2.y ^ tt) |
                    ((unsigned)a2.z ^ tt) | ((unsigned)a2.w ^ tt) |
                    ((unsigned)a3.x ^ tt) | ((unsigned)a3.y ^ tt) |
                    ((unsigned)a3.z ^ tt) | ((unsigned)a3.w ^ tt) |
                    ((unsigned)a4.x ^ tt) | ((unsigned)a4.y ^ tt) |
                    ((unsigned)a4.z ^ tt) | ((unsigned)a4.w ^ tt) |
                    ((unsigned)a5.x ^ tt) | ((unsigned)a5.y ^ tt) |
                    ((unsigned)a5.z ^ tt) | ((unsigned)a5.w ^ tt) |
                    ((unsigned)a6.x ^ tt) | ((unsigned)a6.y ^ tt) |
                    ((unsigned)a6.z ^ tt) | ((unsigned)a6.w ^ tt) |
                    ((unsigned)a7.x ^ tt) | ((unsigned)a7.y ^ tt) |
                    ((unsigned)a7.z ^ tt) | ((unsigned)a7.w ^ tt);
                if ((xr & 0xFFFF0000u) == 0u) break;   // all 32 tags match
                __builtin_amdgcn_s_sleep(2);
            }
            // strip tags, pack bf16 pairs, write 64 B to LDS
            unsigned short* dst = &hlds[t & 1][b_row * LROW + ch * 32];
            int4 d0 = { (int)pk(a0.x, a0.y), (int)pk(a0.z, a0.w),
                        (int)pk(a1.x, a1.y), (int)pk(a1.z, a1.w) };
            int4 d1 = { (int)pk(a2.x, a2.y), (int)pk(a2.z, a2.w),
                        (int)pk(a3.x, a3.y), (int)pk(a3.z, a3.w) };
            int4 d2 = { (int)pk(a4.x, a4.y), (int)pk(a4.z, a4.w),
                        (int)pk(a5.x, a5.y), (int)pk(a5.z, a5.w) };
            int4 d3 = { (int)pk(a6.x, a6.y), (int)pk(a6.z, a6.w),
                        (int)pk(a7.x, a7.y), (int)pk(a7.z, a7.w) };
            *(int4*)(dst + 0)  = d0;
            *(int4*)(dst + 8)  = d1;
            *(int4*)(dst + 16) = d2;
            *(int4*)(dst + 24) = d3;
        }
        __syncthreads();               // the ONLY barrier per step: stage -> read

        // ---- GEMM: D[64x16] = W^T (hi+lo) x H, 16 K-tiles, A in regs, B from LDS ----
        floatx4 acc = {0.f, 0.f, 0.f, 0.f};
        const unsigned short* brow = &hlds[t & 1][c * LROW + q * 8];
        #pragma unroll
        for (int kt = 0; kt < 16; ++kt) {
            short8 bfrag = *(const short8*)(brow + kt * 32);
            acc = __builtin_amdgcn_mfma_f32_16x16x32_bf16(aHi[kt], bfrag, acc, 0, 0, 0);
            acc = __builtin_amdgcn_mfma_f32_16x16x32_bf16(aLo[kt], bfrag, acc, 0, 0, 0);
        }

        // ---- in-lane epilogue: acc[r] = gate r pre-activation (H part) ----
        float xv  = xrow[t];
        float aIv = acc[0] + fmaf(xv, w0I, biasI);
        float aFv = acc[1] + fmaf(xv, w0F, biasF);
        float aCv = acc[2] + fmaf(xv, w0C, biasC);
        float aOv = acc[3] + fmaf(xv, w0O, biasO);
        float I  = fast_sigmoid(aIv);
        float F  = fast_sigmoid(aFv);
        float Ch = fast_tanh(aCv);
        Cst = fmaf(F, Cst, I * Ch);
        float Hn = aOv * fast_tanh(Cst);      // reference: O has NO sigmoid

        if (t < SEQ - 1) {
            // ---- tagged release: ONE relaxed 4-B store per lane. Self-validating:
            //      no vmcnt drain, no flag, no post-epilogue barrier. ----
            unsigned word = (unsigned)f2bf(Hn) | ((unsigned)(t + 1) << 16);
            __hip_atomic_store(pdst_base + ((t + 1) & 1) * SLOTW, word,
                               __ATOMIC_RELAXED, __HIP_MEMORY_SCOPE_AGENT);
        } else {
            int o = bD * HID + colD;
            out[o] = Hn; out[65536 + o] = Hn; out[131072 + o] = Cst;
        }
    }
}

extern "C" void kernel_launch(void* const* d_in, const int* in_sizes, int n_in,
                              void* d_out, int out_size, void* d_ws, size_t ws_size,
                              hipStream_t stream) {
    const float* x  = (const float*)d_in[0];
    const float* H0 = (const float*)d_in[1];
    const float* C0 = (const float*)d_in[2];
    const float* Wi = (const float*)d_in[3];
    const float* bi = (const float*)d_in[4];
    const float* Wf = (const float*)d_in[5];
    const float* bf = (const float*)d_in[6];
    const float* Wc = (const float*)d_in[7];
    const float* bc = (const float*)d_in[8];
    const float* Wo = (const float*)d_in[9];
    const float* bo = (const float*)d_in[10];
    float* out = (float*)d_out;
    unsigned* hw = (unsigned*)d_ws;   // 512 KB: two tagged H slots

    const int init_elems = 2 * SLOTW;
    hipLaunchKernelGGL(lstm_init, dim3((init_elems + 255) / 256), dim3(256), 0, stream,
                       H0, hw);
    hipLaunchKernelGGL(lstm_main, dim3(NGROUP * BPG), dim3(256), 0, stream,
                       x, C0, Wi, bi, Wf, bf, Wc, bc, Wo, bo, out, hw);
}